// Round 1
// baseline (2372.071 us; speedup 1.0000x reference)
//
#include <hip/hip_runtime.h>

typedef _Float16 f16;
typedef _Float16 h2 __attribute__((ext_vector_type(2)));
typedef _Float16 h8 __attribute__((ext_vector_type(8)));
typedef float    f4 __attribute__((ext_vector_type(4)));

#define S_  256
#define B_  1024
#define D_  64
#define H_  128
#define Z_  32
#define BD_ (B_*D_)
#define NSTEP 514

__device__ __forceinline__ float fdot2(h2 a, h2 b, float c) {
#if __has_builtin(__builtin_amdgcn_fdot2)
  return __builtin_amdgcn_fdot2(a, b, c, false);
#else
  return c + (float)a[0]*(float)b[0] + (float)a[1]*(float)b[1];
#endif
}

__device__ __forceinline__ float dot8(h8 a, h8 w, float acc) {
  h2 a0 = __builtin_shufflevector(a, a, 0, 1), w0 = __builtin_shufflevector(w, w, 0, 1);
  h2 a1 = __builtin_shufflevector(a, a, 2, 3), w1 = __builtin_shufflevector(w, w, 2, 3);
  h2 a2 = __builtin_shufflevector(a, a, 4, 5), w2 = __builtin_shufflevector(w, w, 4, 5);
  h2 a3 = __builtin_shufflevector(a, a, 6, 7), w3 = __builtin_shufflevector(w, w, 6, 7);
  acc = fdot2(a0, w0, acc);
  acc = fdot2(a1, w1, acc);
  acc = fdot2(a2, w2, acc);
  acc = fdot2(a3, w3, acc);
  return acc;
}

__device__ __forceinline__ float sigm(float x) { return 1.f / (1.f + __expf(-x)); }
__device__ __forceinline__ float tanh_(float x) {
  float e = __expf(-2.f * fabsf(x));
  float t = (1.f - e) / (1.f + e);
  return copysignf(t, x);
}

// ---------------------------------------------------------------------------
// Kernel 1: reversed-input GRU scan, gi-GEMM fused. 256 blocks x 4 batch rows.
// Per step: 4x384 outputs, dot length 192 (128 h + 64 x), k-split across wave
// pairs (kh = t>>7). Whh in LDS (f16 chunks), Wih in registers (kh==1 threads).
// ---------------------------------------------------------------------------
__global__ __launch_bounds__(256, 1) void gru_kernel(
    const float* __restrict__ xs, const float* __restrict__ Wih,
    const float* __restrict__ Whh, const float* __restrict__ bih,
    const float* __restrict__ bhh, float* __restrict__ hT)
{
  __shared__ h8 WhhC[16][384];      // [k-chunk][row], chunk-major -> conflict-free b128
  __shared__ h8 actH[16][4];        // h (f16) [k-chunk][b]
  __shared__ h8 xv[8][4];           // x (f16) [d-chunk][b]
  __shared__ float part0[128][7];   // kh0 -> partner (b=2,3): r,r,z,z,nh,nh
  __shared__ float part1[128][9];   // kh1 -> partner (b=0,1): r,r,z,z,nh,nh,nx,nx

  const int t  = threadIdx.x;
  const int b0 = blockIdx.x * 4;
  const int jh = t & 127;
  const int kh = t >> 7;

  // stage Whh -> LDS f16 chunks
  for (int i = t; i < 16*384; i += 256) {
    int c = i / 384, row = i % 384;
    const float* src = Whh + row*H_ + c*8;
    h8 w;
    #pragma unroll
    for (int e = 0; e < 8; ++e) w[e] = (f16)src[e];
    WhhC[c][row] = w;
  }
  if (t < 64) { h8 z = {}; actH[t>>2][t&3] = z; }

  // kh==1: cache Wih rows (jh, jh+128, jh+256) in registers
  h8 wxr[8], wxz[8], wxn[8];
  if (kh == 1) {
    #pragma unroll
    for (int c = 0; c < 8; ++c) {
      #pragma unroll
      for (int e = 0; e < 8; ++e) {
        wxr[c][e] = (f16)Wih[(jh      )*D_ + c*8 + e];
        wxz[c][e] = (f16)Wih[(jh + 128)*D_ + c*8 + e];
        wxn[c][e] = (f16)Wih[(jh + 256)*D_ + c*8 + e];
      }
    }
  }
  const float bir = bih[jh], biz = bih[jh+128], bin = bih[jh+256];
  const float bhr = bhh[jh], bhz = bhh[jh+128], bhn = bhh[jh+256];

  // x for s = 0 (reversed: row S-1)
  {
    float x0 = xs[(S_-1)*BD_ + b0*D_ + t];
    int b = t >> 6, d = t & 63;
    ((f16*)xv)[((d>>3)*4 + b)*8 + (d&7)] = (f16)x0;
  }
  float hold0 = 0.f, hold1 = 0.f;   // fp32 master h for b = 2*kh, 2*kh+1
  __syncthreads();

  #pragma unroll 1
  for (int s = 0; s < S_; ++s) {
    float xnext = 0.f;
    if (s < S_-1) xnext = xs[(S_-2-s)*BD_ + b0*D_ + t];  // prefetch next x

    float ar[4] = {0,0,0,0}, az[4] = {0,0,0,0}, an[4] = {0,0,0,0}, anx[4] = {0,0,0,0};
    if (kh == 0) {           // h dims 0..95
      #pragma unroll
      for (int c = 0; c < 12; ++c) {
        h8 wr = WhhC[c][jh], wz = WhhC[c][jh+128], wn = WhhC[c][jh+256];
        #pragma unroll
        for (int b = 0; b < 4; ++b) {
          h8 a = actH[c][b];
          ar[b] = dot8(a, wr, ar[b]);
          az[b] = dot8(a, wz, az[b]);
          an[b] = dot8(a, wn, an[b]);
        }
      }
      part0[jh][0] = ar[2]; part0[jh][1] = ar[3];
      part0[jh][2] = az[2]; part0[jh][3] = az[3];
      part0[jh][4] = an[2]; part0[jh][5] = an[3];
    } else {                 // h dims 96..127 + all of x
      #pragma unroll
      for (int c = 0; c < 4; ++c) {
        int cc = 12 + c;
        h8 wr = WhhC[cc][jh], wz = WhhC[cc][jh+128], wn = WhhC[cc][jh+256];
        #pragma unroll
        for (int b = 0; b < 4; ++b) {
          h8 a = actH[cc][b];
          ar[b] = dot8(a, wr, ar[b]);
          az[b] = dot8(a, wz, az[b]);
          an[b] = dot8(a, wn, an[b]);
        }
      }
      #pragma unroll
      for (int c = 0; c < 8; ++c) {
        #pragma unroll
        for (int b = 0; b < 4; ++b) {
          h8 a = xv[c][b];
          ar[b]  = dot8(a, wxr[c], ar[b]);    // r,z: i+h summed anyway
          az[b]  = dot8(a, wxz[c], az[b]);
          anx[b] = dot8(a, wxn[c], anx[b]);   // n: x-part kept separate (r gates h only)
        }
      }
      part1[jh][0] = ar[0];  part1[jh][1] = ar[1];
      part1[jh][2] = az[0];  part1[jh][3] = az[1];
      part1[jh][4] = an[0];  part1[jh][5] = an[1];
      part1[jh][6] = anx[0]; part1[jh][7] = anx[1];
    }
    __syncthreads();

    // phase C: this thread updates b = 2*kh, 2*kh+1
    {
      float pr0, pz0v, pnh0, pnx0, pr1, pz1v, pnh1, pnx1;
      if (kh == 0) {
        pr0  = ar[0] + part1[jh][0];  pr1  = ar[1] + part1[jh][1];
        pz0v = az[0] + part1[jh][2];  pz1v = az[1] + part1[jh][3];
        pnh0 = an[0] + part1[jh][4];  pnh1 = an[1] + part1[jh][5];
        pnx0 =         part1[jh][6];  pnx1 =         part1[jh][7];
      } else {
        pr0  = ar[2] + part0[jh][0];  pr1  = ar[3] + part0[jh][1];
        pz0v = az[2] + part0[jh][2];  pz1v = az[3] + part0[jh][3];
        pnh0 = an[2] + part0[jh][4];  pnh1 = an[3] + part0[jh][5];
        pnx0 = anx[2];                pnx1 = anx[3];
      }
      float r0  = sigm(pr0 + bir + bhr),  r1  = sigm(pr1 + bir + bhr);
      float zg0 = sigm(pz0v + biz + bhz), zg1 = sigm(pz1v + biz + bhz);
      float n0  = tanh_(pnx0 + bin + r0*(pnh0 + bhn));
      float n1  = tanh_(pnx1 + bin + r1*(pnh1 + bhn));
      hold0 = (1.f - zg0)*n0 + zg0*hold0;
      hold1 = (1.f - zg1)*n1 + zg1*hold1;
      int slot = (jh>>3)*4 + 2*kh;
      ((f16*)actH)[(slot    )*8 + (jh&7)] = (f16)hold0;
      ((f16*)actH)[(slot + 1)*8 + (jh&7)] = (f16)hold1;
    }
    if (s < S_-1) {
      int b = t >> 6, d = t & 63;
      ((f16*)xv)[((d>>3)*4 + b)*8 + (d&7)] = (f16)xnext;
    }
    __syncthreads();
  }
  hT[(b0 + 2*kh    )*H_ + jh] = hold0;
  hT[(b0 + 2*kh + 1)*H_ + jh] = hold1;
}

// ---------------------------------------------------------------------------
// Kernel 2: encoder head + qz0 + z0 sample + KL. 256 blocks x 4 batch rows.
// All fp32 (tiny). logqp0 accumulated into out[1] via per-wave atomics.
// ---------------------------------------------------------------------------
__global__ __launch_bounds__(256) void enc_kernel(
    const float* __restrict__ hT, const float* __restrict__ encW,
    const float* __restrict__ encB, const float* __restrict__ qW,
    const float* __restrict__ qB, const float* __restrict__ eps,
    const float* __restrict__ pm, const float* __restrict__ pls,
    float* __restrict__ z0, float* __restrict__ out)
{
  __shared__ float hTl[4][128];
  __shared__ float ctx[4][64];
  __shared__ float ql[4][64];
  const int t = threadIdx.x;
  const int b0 = blockIdx.x * 4;
  const int lb = t >> 6, j = t & 63;

  for (int i = t; i < 512; i += 256) hTl[i>>7][i&127] = hT[b0*H_ + i];
  __syncthreads();

  float acc = encB[j];
  #pragma unroll
  for (int k = 0; k < 128; k += 4) {
    f4 w = *(const f4*)&encW[j*128 + k];
    acc += hTl[lb][k]*w[0] + hTl[lb][k+1]*w[1] + hTl[lb][k+2]*w[2] + hTl[lb][k+3]*w[3];
  }
  ctx[lb][j] = acc;
  __syncthreads();

  float q = qB[j];
  #pragma unroll
  for (int k = 0; k < 64; k += 4) {
    f4 w = *(const f4*)&qW[j*64 + k];
    q += ctx[lb][k]*w[0] + ctx[lb][k+1]*w[1] + ctx[lb][k+2]*w[2] + ctx[lb][k+3]*w[3];
  }
  ql[lb][j] = q;
  __syncthreads();

  float kl = 0.f;
  if (j < 32) {
    float mean = ql[lb][j], ls = ql[lb][j+32];
    z0[(b0+lb)*Z_ + j] = mean + __expf(ls)*eps[(b0+lb)*Z_ + j];
    float pmj = pm[j], plsj = pls[j];
    float dm = mean - pmj;
    kl = plsj - ls + (__expf(2.f*ls) + dm*dm) / (2.f*__expf(2.f*plsj)) - 0.5f;
  }
  #pragma unroll
  for (int s2 = 32; s2 > 0; s2 >>= 1) kl += __shfl_down(kl, s2, 64);
  if (j == 0) atomicAdd(out + 1, kl * (1.f/1024.f));
}

// ---------------------------------------------------------------------------
// Kernel 3: 514-step SDE scan with fused projection, recon-loss and interp
// output. 256 blocks x 4 batch rows. zs never materialized.
// ---------------------------------------------------------------------------
__global__ __launch_bounds__(256, 1) void sde_kernel(
    const float* __restrict__ z0, const float* __restrict__ ts,
    const float* __restrict__ dW, const float* __restrict__ xs,
    const float* __restrict__ fW1, const float* __restrict__ fb1,
    const float* __restrict__ fW2, const float* __restrict__ fb2,
    const float* __restrict__ fW3, const float* __restrict__ fb3,
    const float* __restrict__ gW1, const float* __restrict__ gb1,
    const float* __restrict__ gW2, const float* __restrict__ gb2,
    const float* __restrict__ pW, const float* __restrict__ pb,
    float* __restrict__ out)
{
  __shared__ h8 W1zC[4][256];       // z-cols of [f_W1; g_W1], rows 0..127 f / 128..255 g
  __shared__ h8 W2C[16][128];
  __shared__ h8 W3G2C[16][64];      // rows 0..31 f_W3, 32..63 g_W2
  __shared__ h8 hAct[48][4];        // chunks 0..15 h1(f), 16..31 gh(g), 32..47 h2
  __shared__ h8 zc[4][4];           // z f16 [z-chunk][b]
  __shared__ float z32[128];        // fp32 master z [b*32+zi]
  __shared__ float part2[128][5];
  __shared__ float part3[64][17];
  __shared__ float projWl[64*33];
  __shared__ float tsL[516];
  __shared__ float lred[4];

  const int t  = threadIdx.x;
  const int b0 = blockIdx.x * 4;

  for (int i = t; i < 4*256; i += 256) {
    int c = i >> 8, r = i & 255;
    const float* src = (r < 128) ? (fW1 + r*33 + 1 + c*8) : (gW1 + (r-128)*33 + 1 + c*8);
    h8 w;
    #pragma unroll
    for (int e = 0; e < 8; ++e) w[e] = (f16)src[e];
    W1zC[c][r] = w;
  }
  for (int i = t; i < 16*128; i += 256) {
    int c = i >> 7, r = i & 127;
    const float* src = fW2 + r*128 + c*8;
    h8 w;
    #pragma unroll
    for (int e = 0; e < 8; ++e) w[e] = (f16)src[e];
    W2C[c][r] = w;
  }
  for (int i = t; i < 16*64; i += 256) {
    int c = i >> 6, r = i & 63;
    const float* src = (r < 32) ? (fW3 + r*128 + c*8) : (gW2 + (r-32)*128 + c*8);
    h8 w;
    #pragma unroll
    for (int e = 0; e < 8; ++e) w[e] = (f16)src[e];
    W3G2C[c][r] = w;
  }
  for (int i = t; i < 64*32; i += 256) {
    int d = i >> 5, zi = i & 31;
    projWl[d*33 + zi] = pW[d*32 + zi];
  }
  for (int i = t; i < 515; i += 256) tsL[i] = ts[i];
  if (t < 128) {
    int b = t >> 5, zi = t & 31;
    float z = z0[(b0+b)*Z_ + zi];
    z32[b*Z_ + zi] = z;
    ((f16*)zc)[((zi>>3)*4 + b)*8 + (zi&7)] = (f16)z;
  }

  const int row = t;                               // phase 1 role
  const float b1v = (row < 128) ? fb1[row] : gb1[row-128];
  const float twv = (row < 128) ? fW1[row*33] : gW1[(row-128)*33];
  const int jh = t & 127, kh = t >> 7;             // phase 2 role
  const float b2v = (t < 128) ? fb2[jh] : 0.f;
  const int r3 = t & 63, kq = t >> 6;              // phase 3 role
  const int ub = t >> 5, uzi = t & 31;             // update role (t<128)
  const float b3v  = (t < 128) ? fb3[uzi] : 0.f;
  const float gb2v = (t < 128) ? gb2[uzi] : 0.f;
  const int pbb = t >> 6, pd = t & 63;             // projection role
  const float pbv = pb[pd];
  float loss = 0.f;
  __syncthreads();

  #pragma unroll 1
  for (int l = 0; l < NSTEP; ++l) {
    float tl  = tsL[l];
    float dt  = tsL[l+1] - tl;
    float sdt = sqrtf(dt);
    float dwv = 0.f;
    if (t < 128) dwv = dW[(l*B_ + b0 + ub)*Z_ + uzi];
    const int ln = l + 1;
    const bool ev = (ln >= 2 && ln <= 512 && (ln & 1) == 0);
    const bool od = (ln >= 3 && ln <= 511 && (ln & 1) == 1);
    float xsv = 0.f;
    if (ev) xsv = xs[(((ln-2)>>1)*B_ + b0 + pbb)*D_ + pd];

    // phase 1: h1 = relu([t,z] @ W1f.T + b), gh = relu([t,z] @ W1g.T + b)
    {
      float base = fmaf(twv, tl, b1v);
      float a0 = base, a1 = base, a2 = base, a3 = base;
      #pragma unroll
      for (int c = 0; c < 4; ++c) {
        h8 w = W1zC[c][row];
        a0 = dot8(zc[c][0], w, a0);
        a1 = dot8(zc[c][1], w, a1);
        a2 = dot8(zc[c][2], w, a2);
        a3 = dot8(zc[c][3], w, a3);
      }
      int sl = (row>>3)*4;
      ((f16*)hAct)[(sl+0)*8 + (row&7)] = (f16)fmaxf(a0, 0.f);
      ((f16*)hAct)[(sl+1)*8 + (row&7)] = (f16)fmaxf(a1, 0.f);
      ((f16*)hAct)[(sl+2)*8 + (row&7)] = (f16)fmaxf(a2, 0.f);
      ((f16*)hAct)[(sl+3)*8 + (row&7)] = (f16)fmaxf(a3, 0.f);
    }
    __syncthreads();

    // phase 2: h2 = relu(h1 @ W2.T + b2), k-split across kh
    float p2[4] = {0,0,0,0};
    #pragma unroll
    for (int c = 0; c < 8; ++c) {
      int cc = kh*8 + c;
      h8 w = W2C[cc][jh];
      p2[0] = dot8(hAct[cc][0], w, p2[0]);
      p2[1] = dot8(hAct[cc][1], w, p2[1]);
      p2[2] = dot8(hAct[cc][2], w, p2[2]);
      p2[3] = dot8(hAct[cc][3], w, p2[3]);
    }
    if (kh == 1) {
      part2[jh][0] = p2[0]; part2[jh][1] = p2[1];
      part2[jh][2] = p2[2]; part2[jh][3] = p2[3];
    }
    __syncthreads();
    if (t < 128) {
      #pragma unroll
      for (int b = 0; b < 4; ++b) {
        float h2v = fmaxf(p2[b] + part2[jh][b] + b2v, 0.f);
        ((f16*)hAct)[((32 + (jh>>3))*4 + b)*8 + (jh&7)] = (f16)h2v;
      }
    }
    __syncthreads();

    // phase 3: drift = h2 @ fW3.T (rows 0..31), diff = gh @ gW2.T (rows 32..63)
    {
      float p3[4] = {0,0,0,0};
      int abase = (r3 < 32) ? 32 : 16;  // h2 chunks vs gh chunks (branchless addr)
      #pragma unroll
      for (int c = 0; c < 4; ++c) {
        int cc = kq*4 + c;
        h8 w = W3G2C[cc][r3];
        p3[0] = dot8(hAct[abase + cc][0], w, p3[0]);
        p3[1] = dot8(hAct[abase + cc][1], w, p3[1]);
        p3[2] = dot8(hAct[abase + cc][2], w, p3[2]);
        p3[3] = dot8(hAct[abase + cc][3], w, p3[3]);
      }
      part3[r3][kq*4+0] = p3[0]; part3[r3][kq*4+1] = p3[1];
      part3[r3][kq*4+2] = p3[2]; part3[r3][kq*4+3] = p3[3];
    }
    __syncthreads();

    // z update (fp32 master)
    if (t < 128) {
      float drift = b3v, diff = gb2v;
      #pragma unroll
      for (int k2 = 0; k2 < 4; ++k2) {
        drift += part3[uzi     ][k2*4 + ub];
        diff  += part3[32 + uzi][k2*4 + ub];
      }
      float z = z32[ub*Z_ + uzi] + drift*dt + diff*(sdt*dwv);
      z32[ub*Z_ + uzi] = z;
      ((f16*)zc)[((uzi>>3)*4 + ub)*8 + (uzi&7)] = (f16)z;
    }
    __syncthreads();

    // fused projection: xs_hat[ln] = z @ proj_W.T + proj_b (fp32)
    if (ev || od) {
      float acc = pbv;
      #pragma unroll
      for (int zi = 0; zi < 32; ++zi)
        acc = fmaf(z32[pbb*Z_ + zi], projWl[pd*33 + zi], acc);
      if (ev) { float d2 = acc - xsv; loss = fmaf(d2, d2, loss); }
      else    out[2 + (((ln-3)>>1)*B_ + b0 + pbb)*D_ + pd] = acc;
    }
  }

  #pragma unroll
  for (int s2 = 32; s2 > 0; s2 >>= 1) loss += __shfl_down(loss, s2, 64);
  if ((t & 63) == 0) lred[t>>6] = loss;
  __syncthreads();
  if (t == 0) {
    float tot = lred[0] + lred[1] + lred[2] + lred[3];
    atomicAdd(out + 0, tot * (1.f/16777216.f));  // mean over 256*1024*64
  }
}

extern "C" void kernel_launch(void* const* d_in, const int* in_sizes, int n_in,
                              void* d_out, int out_size, void* d_ws, size_t ws_size,
                              hipStream_t stream) {
  (void)in_sizes; (void)n_in; (void)out_size; (void)ws_size;
  const float* xs   = (const float*)d_in[0];
  const float* ts   = (const float*)d_in[1];
  const float* eps  = (const float*)d_in[2];
  const float* dWp  = (const float*)d_in[3];
  const float* Wih  = (const float*)d_in[4];
  const float* Whh  = (const float*)d_in[5];
  const float* bih  = (const float*)d_in[6];
  const float* bhh  = (const float*)d_in[7];
  const float* encW = (const float*)d_in[8];
  const float* encB = (const float*)d_in[9];
  const float* qW   = (const float*)d_in[10];
  const float* qB   = (const float*)d_in[11];
  const float* fW1  = (const float*)d_in[12];
  const float* fb1  = (const float*)d_in[13];
  const float* fW2  = (const float*)d_in[14];
  const float* fb2  = (const float*)d_in[15];
  const float* fW3  = (const float*)d_in[16];
  const float* fb3  = (const float*)d_in[17];
  const float* gW1  = (const float*)d_in[18];
  const float* gb1  = (const float*)d_in[19];
  const float* gW2  = (const float*)d_in[20];
  const float* gb2  = (const float*)d_in[21];
  const float* pW   = (const float*)d_in[22];
  const float* pb   = (const float*)d_in[23];
  const float* pm   = (const float*)d_in[24];
  const float* pls  = (const float*)d_in[25];

  float* out = (float*)d_out;
  float* ws  = (float*)d_ws;
  float* hT = ws;              // 1024*128 floats
  float* z0 = ws + 131072;     // 1024*32 floats

  hipMemsetAsync(d_out, 0, 2*sizeof(float), stream);
  hipLaunchKernelGGL(gru_kernel, dim3(256), dim3(256), 0, stream,
                     xs, Wih, Whh, bih, bhh, hT);
  hipLaunchKernelGGL(enc_kernel, dim3(256), dim3(256), 0, stream,
                     hT, encW, encB, qW, qB, eps, pm, pls, z0, out);
  hipLaunchKernelGGL(sde_kernel, dim3(256), dim3(256), 0, stream,
                     z0, ts, dWp, xs, fW1, fb1, fW2, fb2, fW3, fb3,
                     gW1, gb1, gW2, gb2, pW, pb, out);
}

// Round 2
// 1552.562 us; speedup vs baseline: 1.5278x; 1.5278x over previous
//
#include <hip/hip_runtime.h>

typedef _Float16 f16;
typedef _Float16 h2 __attribute__((ext_vector_type(2)));
typedef _Float16 h8 __attribute__((ext_vector_type(8)));
typedef float    f4 __attribute__((ext_vector_type(4)));

#define S_  256
#define B_  1024
#define D_  64
#define H_  128
#define Z_  32
#define BD_ (B_*D_)
#define NSTEP 514

__device__ __forceinline__ float fdot2(h2 a, h2 b, float c) {
#if __has_builtin(__builtin_amdgcn_fdot2)
  return __builtin_amdgcn_fdot2(a, b, c, false);
#else
  return c + (float)a[0]*(float)b[0] + (float)a[1]*(float)b[1];
#endif
}

__device__ __forceinline__ float dot8(h8 a, h8 w, float acc) {
  h2 a0 = __builtin_shufflevector(a, a, 0, 1), w0 = __builtin_shufflevector(w, w, 0, 1);
  h2 a1 = __builtin_shufflevector(a, a, 2, 3), w1 = __builtin_shufflevector(w, w, 2, 3);
  h2 a2 = __builtin_shufflevector(a, a, 4, 5), w2 = __builtin_shufflevector(w, w, 4, 5);
  h2 a3 = __builtin_shufflevector(a, a, 6, 7), w3 = __builtin_shufflevector(w, w, 6, 7);
  acc = fdot2(a0, w0, acc);
  acc = fdot2(a1, w1, acc);
  acc = fdot2(a2, w2, acc);
  acc = fdot2(a3, w3, acc);
  return acc;
}

__device__ __forceinline__ h8 ld8(const float* p) {   // 32B-aligned src
  f4 a = *(const f4*)p;
  f4 b = *(const f4*)(p + 4);
  h8 w;
  w[0]=(f16)a[0]; w[1]=(f16)a[1]; w[2]=(f16)a[2]; w[3]=(f16)a[3];
  w[4]=(f16)b[0]; w[5]=(f16)b[1]; w[6]=(f16)b[2]; w[7]=(f16)b[3];
  return w;
}

__device__ __forceinline__ float sigm(float x) { return 1.f / (1.f + __expf(-x)); }
__device__ __forceinline__ float tanh_(float x) {
  float e = __expf(-2.f * fabsf(x));
  float t = (1.f - e) / (1.f + e);
  return copysignf(t, x);
}

// ---------------------------------------------------------------------------
// GRU: 512 blocks x 2 batch rows, 256 threads. Whh/Wih in REGISTERS
// (thread (jh,kh) owns rows {jh, jh+128, jh+256}, k-half kh: 144 VGPRs).
// Acts broadcast from ~18KB LDS; 2 barriers/step; 2 blocks/CU overlap.
// ---------------------------------------------------------------------------
__global__ __launch_bounds__(256, 2) void gru_kernel(
    const float* __restrict__ xs, const float* __restrict__ Wih,
    const float* __restrict__ Whh, const float* __restrict__ bih,
    const float* __restrict__ bhh, float* __restrict__ hT)
{
  __shared__ h8 actH[16][2];               // h f16 [chunk][b]
  __shared__ h8 xv[8][2];                  // x f16 [chunk][b]
  __shared__ float part[2][2][4][128];     // [kh][b][r,z,nh,nx][jh]

  const int t  = threadIdx.x;
  const int b0 = blockIdx.x * 2;
  const int jh = t & 127;
  const int kh = t >> 7;

  h8 whr[8], whz[8], whn[8], wxr[4], wxz[4], wxn[4];
  {
    const float* pr = Whh + jh*H_        + kh*64;
    const float* pz = Whh + (jh+128)*H_  + kh*64;
    const float* pn = Whh + (jh+256)*H_  + kh*64;
    #pragma unroll
    for (int c = 0; c < 8; ++c) {
      whr[c] = ld8(pr + c*8);
      whz[c] = ld8(pz + c*8);
      whn[c] = ld8(pn + c*8);
    }
    const float* qr = Wih + jh*D_        + kh*32;
    const float* qz = Wih + (jh+128)*D_  + kh*32;
    const float* qn = Wih + (jh+256)*D_  + kh*32;
    #pragma unroll
    for (int c = 0; c < 4; ++c) {
      wxr[c] = ld8(qr + c*8);
      wxz[c] = ld8(qz + c*8);
      wxn[c] = ld8(qn + c*8);
    }
  }
  const int gb = t >> 7, hd = t & 127;     // gate-phase role
  const float bir = bih[hd], biz = bih[hd+128], bin = bih[hd+256];
  const float bhr = bhh[hd], bhz = bhh[hd+128], bhn = bhh[hd+256];
  float hmast = 0.f;

  if (t < 32) { h8 zz = {}; actH[t>>1][t&1] = zz; }
  if (t < 128) {
    int b = t >> 6, d = t & 63;
    float x0 = xs[(S_-1)*BD_ + (b0+b)*D_ + d];
    ((f16*)xv)[((d>>3)*2 + b)*8 + (d&7)] = (f16)x0;
  }
  __syncthreads();

  #pragma unroll 1
  for (int s = 0; s < S_; ++s) {
    float xnext = 0.f;
    if (s < S_-1 && t < 128) {
      int b = t >> 6, d = t & 63;
      xnext = xs[(S_-2-s)*BD_ + (b0+b)*D_ + d];
    }
    // partial dots, 8 independent chains (2 batches x {r,z,nh,(nx)})
    float pr0=0.f, pz0=0.f, pnh0=0.f, pnx0=0.f;
    float pr1=0.f, pz1=0.f, pnh1=0.f, pnx1=0.f;
    #pragma unroll
    for (int c = 0; c < 8; ++c) {
      h8 a0 = actH[kh*8 + c][0];
      h8 a1 = actH[kh*8 + c][1];
      pr0  = dot8(a0, whr[c], pr0);   pr1  = dot8(a1, whr[c], pr1);
      pz0  = dot8(a0, whz[c], pz0);   pz1  = dot8(a1, whz[c], pz1);
      pnh0 = dot8(a0, whn[c], pnh0);  pnh1 = dot8(a1, whn[c], pnh1);
    }
    #pragma unroll
    for (int c = 0; c < 4; ++c) {
      h8 a0 = xv[kh*4 + c][0];
      h8 a1 = xv[kh*4 + c][1];
      pr0  = dot8(a0, wxr[c], pr0);   pr1  = dot8(a1, wxr[c], pr1);
      pz0  = dot8(a0, wxz[c], pz0);   pz1  = dot8(a1, wxz[c], pz1);
      pnx0 = dot8(a0, wxn[c], pnx0);  pnx1 = dot8(a1, wxn[c], pnx1);
    }
    part[kh][0][0][jh] = pr0;   part[kh][1][0][jh] = pr1;
    part[kh][0][1][jh] = pz0;   part[kh][1][1][jh] = pz1;
    part[kh][0][2][jh] = pnh0;  part[kh][1][2][jh] = pnh1;
    part[kh][0][3][jh] = pnx0;  part[kh][1][3][jh] = pnx1;
    __syncthreads();

    // gate math: thread (gb, hd) owns h[gb][hd] master fp32
    {
      float pr  = part[0][gb][0][hd] + part[1][gb][0][hd];
      float pz  = part[0][gb][1][hd] + part[1][gb][1][hd];
      float pnh = part[0][gb][2][hd] + part[1][gb][2][hd];
      float pnx = part[0][gb][3][hd] + part[1][gb][3][hd];
      float r  = sigm(pr + bir + bhr);
      float zg = sigm(pz + biz + bhz);
      float n  = tanh_(pnx + bin + r*(pnh + bhn));
      hmast = (1.f - zg)*n + zg*hmast;
      ((f16*)actH)[((hd>>3)*2 + gb)*8 + (hd&7)] = (f16)hmast;
    }
    if (s < S_-1 && t < 128) {
      int b = t >> 6, d = t & 63;
      ((f16*)xv)[((d>>3)*2 + b)*8 + (d&7)] = (f16)xnext;
    }
    __syncthreads();
  }
  hT[(b0 + gb)*H_ + hd] = hmast;
}

// ---------------------------------------------------------------------------
// Encoder head (unchanged; tiny): 256 blocks x 4 rows.
// ---------------------------------------------------------------------------
__global__ __launch_bounds__(256) void enc_kernel(
    const float* __restrict__ hT, const float* __restrict__ encW,
    const float* __restrict__ encB, const float* __restrict__ qW,
    const float* __restrict__ qB, const float* __restrict__ eps,
    const float* __restrict__ pm, const float* __restrict__ pls,
    float* __restrict__ z0, float* __restrict__ out)
{
  __shared__ float hTl[4][128];
  __shared__ float ctx[4][64];
  __shared__ float ql[4][64];
  const int t = threadIdx.x;
  const int b0 = blockIdx.x * 4;
  const int lb = t >> 6, j = t & 63;

  for (int i = t; i < 512; i += 256) hTl[i>>7][i&127] = hT[b0*H_ + i];
  __syncthreads();

  float acc = encB[j];
  #pragma unroll
  for (int k = 0; k < 128; k += 4) {
    f4 w = *(const f4*)&encW[j*128 + k];
    acc += hTl[lb][k]*w[0] + hTl[lb][k+1]*w[1] + hTl[lb][k+2]*w[2] + hTl[lb][k+3]*w[3];
  }
  ctx[lb][j] = acc;
  __syncthreads();

  float q = qB[j];
  #pragma unroll
  for (int k = 0; k < 64; k += 4) {
    f4 w = *(const f4*)&qW[j*64 + k];
    q += ctx[lb][k]*w[0] + ctx[lb][k+1]*w[1] + ctx[lb][k+2]*w[2] + ctx[lb][k+3]*w[3];
  }
  ql[lb][j] = q;
  __syncthreads();

  float kl = 0.f;
  if (j < 32) {
    float mean = ql[lb][j], ls = ql[lb][j+32];
    z0[(b0+lb)*Z_ + j] = mean + __expf(ls)*eps[(b0+lb)*Z_ + j];
    float pmj = pm[j], plsj = pls[j];
    float dm = mean - pmj;
    kl = plsj - ls + (__expf(2.f*ls) + dm*dm) / (2.f*__expf(2.f*plsj)) - 0.5f;
  }
  #pragma unroll
  for (int s2 = 32; s2 > 0; s2 >>= 1) kl += __shfl_down(kl, s2, 64);
  if (j == 0) atomicAdd(out + 1, kl * (1.f/1024.f));
}

// ---------------------------------------------------------------------------
// SDE: 512 blocks x 2 batch rows, 256 threads. All weights in registers
// (~160 VGPR), acts broadcast from ~4KB LDS, 3 barriers/step, z master in
// registers, drift/diff exchange via shfl_xor, proj from f16 zc.
// ---------------------------------------------------------------------------
__global__ __launch_bounds__(256, 2) void sde_kernel(
    const float* __restrict__ z0, const float* __restrict__ ts,
    const float* __restrict__ dW, const float* __restrict__ xs,
    const float* __restrict__ fW1, const float* __restrict__ fb1,
    const float* __restrict__ fW2, const float* __restrict__ fb2,
    const float* __restrict__ fW3, const float* __restrict__ fb3,
    const float* __restrict__ gW1, const float* __restrict__ gb1,
    const float* __restrict__ gW2, const float* __restrict__ gb2,
    const float* __restrict__ pW, const float* __restrict__ pb,
    float* __restrict__ out)
{
  __shared__ h8 hAct[48][2];     // chunks 0..15 h1(f), 16..31 gh(g), 32..47 h2
  __shared__ h8 zc[4][2];        // z f16 [chunk][b]
  __shared__ float tsL[516];
  __shared__ float lred[2];

  const int t  = threadIdx.x;
  const int b0 = blockIdx.x * 2;

  // --- phase-1 role: row t of [fW1; gW1] ---
  const int row = t;
  const float* w1src = (row < 128) ? (fW1 + row*33) : (gW1 + (row-128)*33);
  const float twv = w1src[0];
  const float b1v = (row < 128) ? fb1[row] : gb1[row-128];
  h8 w1z[4];
  #pragma unroll
  for (int c = 0; c < 4; ++c) {       // stride-33 rows: scalar loads (startup only)
    h8 w;
    #pragma unroll
    for (int e = 0; e < 8; ++e) w[e] = (f16)w1src[1 + c*8 + e];
    w1z[c] = w;
  }
  // --- phase-2 role: (jh, p2b) -> h2[p2b][jh] ---
  const int jh = t & 127; const int p2b = t >> 7;
  const float b2v = fb2[jh];
  h8 w2[16];
  {
    const float* p = fW2 + jh*H_;
    #pragma unroll
    for (int c = 0; c < 16; ++c) w2[c] = ld8(p + c*8);
  }
  // --- phase-3 role (t>=128): rr<32 drift row rr, rr>=32 diff row rr-32 ---
  const int rr = t & 63; const int b3 = (t >> 6) & 1;
  h8 w3[16];
  float b3v = 0.f;
  if (t >= 128) {
    const float* p = (rr < 32) ? (fW3 + rr*H_) : (gW2 + (rr-32)*H_);
    #pragma unroll
    for (int c = 0; c < 16; ++c) w3[c] = ld8(p + c*8);
    b3v = (rr < 32) ? fb3[rr] : gb2[rr-32];
  }
  // --- proj role (t<128): (pbb, pd) ---
  const int pbb = t >> 6; const int pd = t & 63;
  h8 pw[4];
  float pbv = 0.f;
  if (t < 128) {
    const float* p = pW + pd*Z_;
    #pragma unroll
    for (int c = 0; c < 4; ++c) pw[c] = ld8(p + c*8);
    pbv = pb[pd];
  }

  for (int i = t; i < 515; i += 256) tsL[i] = ts[i];
  float zm = 0.f;                     // fp32 z master at (t>=128, rr<32) lanes
  if (t >= 128 && rr < 32) {
    zm = z0[(b0 + b3)*Z_ + rr];
    ((f16*)zc)[((rr>>3)*2 + b3)*8 + (rr&7)] = (f16)zm;
  }
  float loss = 0.f;
  __syncthreads();

  #pragma unroll 1
  for (int l = 0; l < NSTEP; ++l) {
    const float tl  = tsL[l];
    const float dt  = tsL[l+1] - tl;
    const float sdt = sqrtf(dt);
    const int ln = l + 1;
    const bool ev = ((ln & 1) == 0) && ln >= 2 && ln <= 512;
    const bool od = ((ln & 1) == 1) && ln >= 3 && ln <= 511;
    float dwv = 0.f;
    if (t >= 128 && rr < 32) dwv = dW[(l*B_ + b0 + b3)*Z_ + rr];
    float xsv = 0.f;
    if (ev && t < 128) xsv = xs[(((ln-2)>>1)*B_ + b0 + pbb)*D_ + pd];

    // phase 1: h1/gh = relu([t,z] @ W1.T + b), both batches per thread
    {
      float a0 = fmaf(twv, tl, b1v), a1 = a0;
      #pragma unroll
      for (int c = 0; c < 4; ++c) {
        a0 = dot8(zc[c][0], w1z[c], a0);
        a1 = dot8(zc[c][1], w1z[c], a1);
      }
      a0 = fmaxf(a0, 0.f); a1 = fmaxf(a1, 0.f);
      const int ch = (row < 128) ? (row >> 3) : (16 + ((row - 128) >> 3));
      ((f16*)hAct)[(ch*2 + 0)*8 + (row&7)] = (f16)a0;
      ((f16*)hAct)[(ch*2 + 1)*8 + (row&7)] = (f16)a1;
    }
    __syncthreads();   // A

    // phase 2: h2 = relu(h1 @ W2.T + b2), full k, 4 acc chains
    {
      float c0 = 0.f, c1 = 0.f, c2 = 0.f, c3 = 0.f;
      #pragma unroll
      for (int c = 0; c < 16; c += 4) {
        c0 = dot8(hAct[c    ][p2b], w2[c    ], c0);
        c1 = dot8(hAct[c + 1][p2b], w2[c + 1], c1);
        c2 = dot8(hAct[c + 2][p2b], w2[c + 2], c2);
        c3 = dot8(hAct[c + 3][p2b], w2[c + 3], c3);
      }
      float acc = fmaxf(b2v + (c0 + c1) + (c2 + c3), 0.f);
      ((f16*)hAct)[((32 + (jh>>3))*2 + p2b)*8 + (jh&7)] = (f16)acc;
    }
    __syncthreads();   // B

    // phase 3 (waves 2,3): drift/diff full-k dots; exchange via shfl_xor; z update
    if (t >= 128) {
      const int abase = (rr < 32) ? 32 : 16;   // drift reads h2, diff reads gh
      float c0 = 0.f, c1 = 0.f, c2 = 0.f, c3 = 0.f;
      #pragma unroll
      for (int c = 0; c < 16; c += 4) {
        c0 = dot8(hAct[abase + c    ][b3], w3[c    ], c0);
        c1 = dot8(hAct[abase + c + 1][b3], w3[c + 1], c1);
        c2 = dot8(hAct[abase + c + 2][b3], w3[c + 2], c2);
        c3 = dot8(hAct[abase + c + 3][b3], w3[c + 3], c3);
      }
      float acc = b3v + (c0 + c1) + (c2 + c3);
      float other = __shfl_xor(acc, 32, 64);   // lane zi <-> lane zi+32
      if (rr < 32) {
        zm += acc*dt + other*(sdt*dwv);
        ((f16*)zc)[((rr>>3)*2 + b3)*8 + (rr&7)] = (f16)zm;
      }
    }
    __syncthreads();   // C

    // fused projection (waves 0,1) on needed steps
    if ((ev || od) && t < 128) {
      float c0 = 0.f, c1 = 0.f;
      c0 = dot8(zc[0][pbb], pw[0], c0);
      c1 = dot8(zc[1][pbb], pw[1], c1);
      c0 = dot8(zc[2][pbb], pw[2], c0);
      c1 = dot8(zc[3][pbb], pw[3], c1);
      float acc = pbv + c0 + c1;
      if (ev) { float d2 = acc - xsv; loss = fmaf(d2, d2, loss); }
      else out[2 + (((ln-3)>>1)*B_ + b0 + pbb)*D_ + pd] = acc;
    }
  }

  #pragma unroll
  for (int s2 = 32; s2 > 0; s2 >>= 1) loss += __shfl_down(loss, s2, 64);
  if (t == 0)  lred[0] = loss;
  if (t == 64) lred[1] = loss;
  __syncthreads();
  if (t == 0) atomicAdd(out + 0, (lred[0] + lred[1]) * (1.f/16777216.f));
}

extern "C" void kernel_launch(void* const* d_in, const int* in_sizes, int n_in,
                              void* d_out, int out_size, void* d_ws, size_t ws_size,
                              hipStream_t stream) {
  (void)in_sizes; (void)n_in; (void)out_size; (void)ws_size;
  const float* xs   = (const float*)d_in[0];
  const float* ts   = (const float*)d_in[1];
  const float* eps  = (const float*)d_in[2];
  const float* dWp  = (const float*)d_in[3];
  const float* Wih  = (const float*)d_in[4];
  const float* Whh  = (const float*)d_in[5];
  const float* bih  = (const float*)d_in[6];
  const float* bhh  = (const float*)d_in[7];
  const float* encW = (const float*)d_in[8];
  const float* encB = (const float*)d_in[9];
  const float* qW   = (const float*)d_in[10];
  const float* qB   = (const float*)d_in[11];
  const float* fW1  = (const float*)d_in[12];
  const float* fb1  = (const float*)d_in[13];
  const float* fW2  = (const float*)d_in[14];
  const float* fb2  = (const float*)d_in[15];
  const float* fW3  = (const float*)d_in[16];
  const float* fb3  = (const float*)d_in[17];
  const float* gW1  = (const float*)d_in[18];
  const float* gb1  = (const float*)d_in[19];
  const float* gW2  = (const float*)d_in[20];
  const float* gb2  = (const float*)d_in[21];
  const float* pW   = (const float*)d_in[22];
  const float* pb   = (const float*)d_in[23];
  const float* pm   = (const float*)d_in[24];
  const float* pls  = (const float*)d_in[25];

  float* out = (float*)d_out;
  float* ws  = (float*)d_ws;
  float* hT = ws;              // 1024*128 floats
  float* z0 = ws + 131072;     // 1024*32 floats

  hipMemsetAsync(d_out, 0, 2*sizeof(float), stream);
  hipLaunchKernelGGL(gru_kernel, dim3(512), dim3(256), 0, stream,
                     xs, Wih, Whh, bih, bhh, hT);
  hipLaunchKernelGGL(enc_kernel, dim3(256), dim3(256), 0, stream,
                     hT, encW, encB, qW, qB, eps, pm, pls, z0, out);
  hipLaunchKernelGGL(sde_kernel, dim3(512), dim3(256), 0, stream,
                     z0, ts, dWp, xs, fW1, fb1, fW2, fb2, fW3, fb3,
                     gW1, gb1, gW2, gb2, pW, pb, out);
}